// Round 9
// baseline (1225.706 us; speedup 1.0000x reference)
//
#include <hip/hip_runtime.h>

// Luenberger state estimator: T=2048 sequential steps, B=1024 elements.
// R9: TWO INDEPENDENT elements per wave, statically interleaved.
//   grid = 512 blocks x 64 threads; wave w owns elements (2w, 2w+1).
//   Two independent recurrence chains in one instruction stream -> each
//   element's dependency stalls are filled by the other's instructions
//   (R8 proved fill works: VALUBusy 55->78%; but redundant work cost 2x.
//   Here the fill is USEFUL work). Weights shared (uniforms -> SGPRs).
//   u/y elements 2w,2w+1 are adjacent -> one dwordx4 load serves both.
// All mechanisms R6-proven: op_sel splats, swap32 fold + 5-stage DPP
// half-reduce + direction probe, 4-step ping-pong prefetch.

#define T_STEPS 2048
#define B_SZ    1024
#define NX      8
#define HID     64

typedef float v2f __attribute__((ext_vector_type(2)));
typedef float v4f __attribute__((ext_vector_type(4)));

// d = a*b + c
__device__ __forceinline__ v2f pk_fma(v2f a, v2f b, v2f c) {
  v2f d;
  asm("v_pk_fma_f32 %0, %1, %2, %3" : "=v"(d) : "v"(a), "v"(b), "v"(c));
  return d;
}
// acc += a*b
__device__ __forceinline__ void pk_fma_acc(v2f& acc, v2f a, v2f b) {
  asm("v_pk_fma_f32 %0, %1, %2, %0" : "+v"(acc) : "v"(a), "v"(b));
}
// d = splat_lo(a)*b + c   (PROVEN R6)
__device__ __forceinline__ v2f pk_fma_s0lo(v2f a, v2f b, v2f c) {
  v2f d;
  asm("v_pk_fma_f32 %0, %1, %2, %3 op_sel:[0,0,0] op_sel_hi:[0,1,1]"
      : "=v"(d) : "v"(a), "v"(b), "v"(c));
  return d;
}
// d = splat_hi(a)*b + c   (PROVEN R6)
__device__ __forceinline__ v2f pk_fma_s0hi(v2f a, v2f b, v2f c) {
  v2f d;
  asm("v_pk_fma_f32 %0, %1, %2, %3 op_sel:[1,0,0] op_sel_hi:[1,1,1]"
      : "=v"(d) : "v"(a), "v"(b), "v"(c));
  return d;
}
// acc += a*splat_lo(b)    (PROVEN R6)
__device__ __forceinline__ void pk_fma_acc_s1lo(v2f& acc, v2f a, v2f b) {
  asm("v_pk_fma_f32 %0, %1, %2, %0 op_sel:[0,0,0] op_sel_hi:[1,0,1]"
      : "+v"(acc) : "v"(a), "v"(b));
}
// acc += a*splat_hi(b)    (PROVEN R6)
__device__ __forceinline__ void pk_fma_acc_s1hi(v2f& acc, v2f a, v2f b) {
  asm("v_pk_fma_f32 %0, %1, %2, %0 op_sel:[0,1,0] op_sel_hi:[1,1,1]"
      : "+v"(acc) : "v"(a), "v"(b));
}

// tanh pair: inputs pre-scaled by 2*log2(e); returns {tanh(a), tanh(b)}
__device__ __forceinline__ v2f tanh_pair(float pa, float pb) {
  v2f r;
  r[0] = __builtin_amdgcn_rcpf(__builtin_amdgcn_exp2f(pa) + 1.0f);
  r[1] = __builtin_amdgcn_rcpf(__builtin_amdgcn_exp2f(pb) + 1.0f);
  v2f h;
  h[0] = fmaf(-2.0f, r[0], 1.0f);
  h[1] = fmaf(-2.0f, r[1], 1.0f);
  return h;
}

template <int CTRL, int RMASK>
__device__ __forceinline__ float dpp_add(float acc) {
  int moved = __builtin_amdgcn_update_dpp(0, __float_as_int(acc), CTRL, RMASK, 0xf, true);
  return acc + __int_as_float(moved);
}

// after this, lane 31 = sum(lanes 0..31), lane 63 = sum(lanes 32..63)
__device__ __forceinline__ float half_reduce(float c) {
  c = dpp_add<0x111, 0xf>(c);  // row_shr:1
  c = dpp_add<0x112, 0xf>(c);  // row_shr:2
  c = dpp_add<0x114, 0xf>(c);  // row_shr:4
  c = dpp_add<0x118, 0xf>(c);  // row_shr:8
  c = dpp_add<0x142, 0xa>(c);  // row_bcast:15 into rows 1,3
  return c;
}

__device__ __forceinline__ void swap32(float& a, float& b) {
  asm("v_permlane32_swap_b32 %0, %1" : "+v"(a), "+v"(b));
}

__device__ __forceinline__ float rlf(float v, int lane) {
  return __int_as_float(__builtin_amdgcn_readlane(__float_as_int(v), lane));
}

__global__ __launch_bounds__(64, 1) void luen_kernel(
    const float* __restrict__ u, const float* __restrict__ y,
    const float* __restrict__ Wf1, const float* __restrict__ bf1,
    const float* __restrict__ Wf2, const float* __restrict__ bf2,
    const float* __restrict__ Wg, const float* __restrict__ bg,
    const float* __restrict__ Wk1, const float* __restrict__ bk1,
    const float* __restrict__ Wk2, const float* __restrict__ bk2,
    float* __restrict__ out) {
  const int bid = blockIdx.x;       // owns elements 2*bid, 2*bid+1
  const int h   = threadIdx.x;

  const float TS = 2.885390081777927f;  // 2*log2(e)
  const float INV64 = 1.0f / 64.0f;

  // ---- per-lane weight columns (shared by both elements) ----
  v2f wf1p[5];
#pragma unroll
  for (int p = 0; p < 5; ++p)
    wf1p[p] = v2f{TS * Wf1[(2 * p) * HID + h], TS * Wf1[(2 * p + 1) * HID + h]};
  v2f wk1p[4];
#pragma unroll
  for (int p = 0; p < 4; ++p)
    wk1p[p] = v2f{TS * Wk1[(2 * p) * HID + h], TS * Wk1[(2 * p + 1) * HID + h]};

  v2f wf2p[4], bf2sp[4];
#pragma unroll
  for (int p = 0; p < 4; ++p) {
    wf2p[p]  = v2f{Wf2[h * NX + 2 * p], Wf2[h * NX + 2 * p + 1]};
    bf2sp[p] = v2f{INV64 * bf2[2 * p], INV64 * bf2[2 * p + 1]};
  }
  v2f wk2e[4], wk2o[4], bk2se[4], bk2so[4];
#pragma unroll
  for (int p = 0; p < 4; ++p) {
    const float* r = Wk2 + h * (NX * 2);
    wk2e[p]  = v2f{r[4 * p], r[4 * p + 2]};
    wk2o[p]  = v2f{r[4 * p + 1], r[4 * p + 3]};
    bk2se[p] = v2f{INV64 * bk2[4 * p], INV64 * bk2[4 * p + 2]};
    bk2so[p] = v2f{INV64 * bk2[4 * p + 1], INV64 * bk2[4 * p + 3]};
  }
  v2f wgc0[4], wgc1[4];
#pragma unroll
  for (int p = 0; p < 4; ++p) {
    wgc0[p] = v2f{Wg[4 * p], Wg[4 * p + 2]};
    wgc1[p] = v2f{Wg[4 * p + 1], Wg[4 * p + 3]};
  }
  const v2f a0i = v2f{bg[0], 0.0f};
  const v2f a1i = v2f{bg[1], 0.0f};
  const v2f pfi = v2f{TS * bf1[h], 0.0f};
  const v2f pki = v2f{TS * bk1[h], 0.0f};

  // ---- permlane32_swap direction probe (one-time; proven) ----
  float probe = (h < 32) ? 0.0f : 1.0f;
  float zf = 0.0f;
  swap32(probe, zf);
  const bool dir1 = __builtin_amdgcn_readlane(__float_as_int(probe), 32) != 0;
  const int laneA = dir1 ? 63 : 31;  // sum of c[j]
  const int laneB = dir1 ? 31 : 63;  // sum of c[j+4]

  // u/y rows: [t][B][2] floats; elements 2b,2b+1 = one contiguous v4f
  const v4f* __restrict__ pu = reinterpret_cast<const v4f*>(u) + bid;
  const v4f* __restrict__ py = reinterpret_cast<const v4f*>(y) + bid;
  const int STR4 = B_SZ / 2;  // per-t stride in v4f

  v2f xA[4], xB[4];
#pragma unroll
  for (int p = 0; p < 4; ++p) { xA[p] = v2f{0.0f, 0.0f}; xB[p] = v2f{0.0f, 0.0f}; }

  v4f Gu[4], Gy[4], Hu[4], Hy[4];

#define LOADG(SU_, SY_)                              \
  {                                                  \
    SU_[0] = pu[0 * STR4]; SU_[1] = pu[1 * STR4];    \
    SU_[2] = pu[2 * STR4]; SU_[3] = pu[3 * STR4];    \
    SY_[0] = py[0 * STR4]; SY_[1] = py[1 * STR4];    \
    SY_[2] = py[2 * STR4]; SY_[3] = py[3 * STR4];    \
    pu += 4 * STR4; py += 4 * STR4;                  \
  }

// one c-quarter for one element (R6-proven op_sel block)
#define CQ(HP_, EP_, P_, CLO_, CHI_)                                          \
  {                                                                           \
    v2f t0 = pk_fma_s0hi(HP_, wk2e[P_], bk2se[P_]);                           \
    v2f t1 = pk_fma_s0hi(HP_, wk2o[P_], bk2so[P_]);                           \
    v2f cp = pk_fma_s0lo(HP_, wf2p[P_], bf2sp[P_]);                           \
    pk_fma_acc_s1lo(cp, t0, EP_);                                             \
    pk_fma_acc_s1hi(cp, t1, EP_);                                             \
    CLO_ = cp[0]; CHI_ = cp[1];                                               \
  }

#define STEP2(U4_, Y4_)                                                       \
  {                                                                           \
    const v4f u4 = (U4_);                                                     \
    const v4f y4 = (Y4_);                                                     \
    const v2f cuA = v2f{u4.x, u4.y}, cuB = v2f{u4.z, u4.w};                   \
    const v2f cyA = v2f{y4.x, y4.y}, cyB = v2f{y4.z, y4.w};                   \
    /* y_hat + error, both elements interleaved */                            \
    v2f a0A = pk_fma(xA[0], wgc0[0], a0i);                                    \
    v2f a0B = pk_fma(xB[0], wgc0[0], a0i);                                    \
    v2f a1A = pk_fma(xA[0], wgc1[0], a1i);                                    \
    v2f a1B = pk_fma(xB[0], wgc1[0], a1i);                                    \
    pk_fma_acc(a0A, xA[1], wgc0[1]); pk_fma_acc(a0B, xB[1], wgc0[1]);         \
    pk_fma_acc(a1A, xA[1], wgc1[1]); pk_fma_acc(a1B, xB[1], wgc1[1]);         \
    pk_fma_acc(a0A, xA[2], wgc0[2]); pk_fma_acc(a0B, xB[2], wgc0[2]);         \
    pk_fma_acc(a1A, xA[2], wgc1[2]); pk_fma_acc(a1B, xB[2], wgc1[2]);         \
    pk_fma_acc(a0A, xA[3], wgc0[3]); pk_fma_acc(a0B, xB[3], wgc0[3]);         \
    pk_fma_acc(a1A, xA[3], wgc1[3]); pk_fma_acc(a1B, xB[3], wgc1[3]);         \
    v2f epA, epB;                                                             \
    epA[0] = a0A[0] + a0A[1] - cyA[0]; epA[1] = a1A[0] + a1A[1] - cyA[1];     \
    epB[0] = a0B[0] + a0B[1] - cyB[0]; epB[1] = a1B[0] + a1B[1] - cyB[1];     \
    /* f-net / k-net pre-activations, interleaved */                          \
    v2f pfA = pk_fma(xA[0], wf1p[0], pfi);                                    \
    v2f pfB = pk_fma(xB[0], wf1p[0], pfi);                                    \
    pk_fma_acc(pfA, xA[1], wf1p[1]); pk_fma_acc(pfB, xB[1], wf1p[1]);         \
    pk_fma_acc(pfA, xA[2], wf1p[2]); pk_fma_acc(pfB, xB[2], wf1p[2]);         \
    pk_fma_acc(pfA, xA[3], wf1p[3]); pk_fma_acc(pfB, xB[3], wf1p[3]);         \
    pk_fma_acc(pfA, cuA, wf1p[4]);   pk_fma_acc(pfB, cuB, wf1p[4]);           \
    v2f pkA = pk_fma(xA[0], wk1p[0], pki);                                    \
    v2f pkB = pk_fma(xB[0], wk1p[0], pki);                                    \
    pk_fma_acc(pkA, xA[1], wk1p[1]); pk_fma_acc(pkB, xB[1], wk1p[1]);         \
    pk_fma_acc(pkA, xA[2], wk1p[2]); pk_fma_acc(pkB, xB[2], wk1p[2]);         \
    pk_fma_acc(pkA, xA[3], wk1p[3]); pk_fma_acc(pkB, xB[3], wk1p[3]);         \
    const v2f hpA = tanh_pair(pfA[0] + pfA[1], pkA[0] + pkA[1]);              \
    const v2f hpB = tanh_pair(pfB[0] + pfB[1], pkB[0] + pkB[1]);              \
    /* per-lane contributions */                                              \
    float cA0, cA1, cA2, cA3, cA4, cA5, cA6, cA7;                             \
    float cB0, cB1, cB2, cB3, cB4, cB5, cB6, cB7;                             \
    CQ(hpA, epA, 0, cA0, cA1) CQ(hpB, epB, 0, cB0, cB1)                       \
    CQ(hpA, epA, 1, cA2, cA3) CQ(hpB, epB, 1, cB2, cB3)                       \
    CQ(hpA, epA, 2, cA4, cA5) CQ(hpB, epB, 2, cB4, cB5)                       \
    CQ(hpA, epA, 3, cA6, cA7) CQ(hpB, epB, 3, cB6, cB7)                       \
    /* swap32 fold + half-reduce, both elements interleaved */                \
    swap32(cA0, cA4); swap32(cB0, cB4);                                       \
    swap32(cA1, cA5); swap32(cB1, cB5);                                       \
    swap32(cA2, cA6); swap32(cB2, cB6);                                       \
    swap32(cA3, cA7); swap32(cB3, cB7);                                       \
    float dA0 = cA0 + cA4, dB0 = cB0 + cB4;                                   \
    float dA1 = cA1 + cA5, dB1 = cB1 + cB5;                                   \
    float dA2 = cA2 + cA6, dB2 = cB2 + cB6;                                   \
    float dA3 = cA3 + cA7, dB3 = cB3 + cB7;                                   \
    dA0 = half_reduce(dA0); dB0 = half_reduce(dB0);                           \
    dA1 = half_reduce(dA1); dB1 = half_reduce(dB1);                           \
    dA2 = half_reduce(dA2); dB2 = half_reduce(dB2);                           \
    dA3 = half_reduce(dA3); dB3 = half_reduce(dB3);                           \
    xA[0][0] += rlf(dA0, laneA); xB[0][0] += rlf(dB0, laneA);                 \
    xA[0][1] += rlf(dA1, laneA); xB[0][1] += rlf(dB1, laneA);                 \
    xA[1][0] += rlf(dA2, laneA); xB[1][0] += rlf(dB2, laneA);                 \
    xA[1][1] += rlf(dA3, laneA); xB[1][1] += rlf(dB3, laneA);                 \
    xA[2][0] += rlf(dA0, laneB); xB[2][0] += rlf(dB0, laneB);                 \
    xA[2][1] += rlf(dA1, laneB); xB[2][1] += rlf(dB1, laneB);                 \
    xA[3][0] += rlf(dA2, laneB); xB[3][0] += rlf(dB2, laneB);                 \
    xA[3][1] += rlf(dA3, laneB); xB[3][1] += rlf(dB3, laneB);                 \
  }

  LOADG(Gu, Gy);
  LOADG(Hu, Hy);

  for (int it = 0; it < 255; ++it) {
    STEP2(Gu[0], Gy[0]); STEP2(Gu[1], Gy[1]);
    STEP2(Gu[2], Gy[2]); STEP2(Gu[3], Gy[3]);
    LOADG(Gu, Gy);
    STEP2(Hu[0], Hy[0]); STEP2(Hu[1], Hy[1]);
    STEP2(Hu[2], Hy[2]); STEP2(Hu[3], Hy[3]);
    LOADG(Hu, Hy);
  }
  STEP2(Gu[0], Gy[0]); STEP2(Gu[1], Gy[1]);
  STEP2(Gu[2], Gy[2]); STEP2(Gu[3], Gy[3]);
  STEP2(Hu[0], Hy[0]); STEP2(Hu[1], Hy[1]);
  STEP2(Hu[2], Hy[2]); STEP2(Hu[3], Hy[3]);
#undef STEP2
#undef CQ
#undef LOADG

  if (h == 0) {
    const int ebA = 2 * bid, ebB = 2 * bid + 1;
#pragma unroll
    for (int p = 0; p < 4; ++p) {
      out[ebA * NX + 2 * p]     = xA[p][0];
      out[ebA * NX + 2 * p + 1] = xA[p][1];
      out[ebB * NX + 2 * p]     = xB[p][0];
      out[ebB * NX + 2 * p + 1] = xB[p][1];
    }
  }
}

extern "C" void kernel_launch(void* const* d_in, const int* in_sizes, int n_in,
                              void* d_out, int out_size, void* d_ws, size_t ws_size,
                              hipStream_t stream) {
  const float* u   = (const float*)d_in[0];
  const float* y   = (const float*)d_in[1];
  const float* Wf1 = (const float*)d_in[2];
  const float* bf1 = (const float*)d_in[3];
  const float* Wf2 = (const float*)d_in[4];
  const float* bf2 = (const float*)d_in[5];
  const float* Wg  = (const float*)d_in[6];
  const float* bg  = (const float*)d_in[7];
  const float* Wk1 = (const float*)d_in[8];
  const float* bk1 = (const float*)d_in[9];
  const float* Wk2 = (const float*)d_in[10];
  const float* bk2 = (const float*)d_in[11];

  luen_kernel<<<dim3(B_SZ / 2), dim3(HID), 0, stream>>>(
      u, y, Wf1, bf1, Wf2, bf2, Wg, bg, Wk1, bk1, Wk2, bk2, (float*)d_out);
}

// Round 11
// 665.709 us; speedup vs baseline: 1.8412x; 1.8412x over previous
//
#include <hip/hip_runtime.h>

// Luenberger state estimator: T=2048 sequential steps, B=1024 independent
// elements. 1 wave/element (1024 blocks x 64 threads), lane h = hidden unit h
// of BOTH MLPs. R11 = EXACT revert to proven R6 (664us, passed):
//  - v_pk_fma_f32 packed fp32 everywhere (2 FMA/instr), tied accumulators
//  - VOP3P op_sel word-select splats in the c-block (proven R6)
//  - swap32 fold + 5-stage builtin-DPP half-reduce + direction probe
//    (builtin update_dpp: compiler inserts required DPP hazard nops;
//     R10's raw-asm DPP violated VALU->DPP wait states -> garbage)
//  - NO permlane16_swap (R5: broken/mixing semantics on this HW)
//  - 4-step ping-pong A/B group prefetch of u/y
// Post-R10 ledger: co-residency (R8), work-split (R7), in-wave ILP (R9),
// further instruction diet -- all measured dead ends. This is the floor.

#define T_STEPS 2048
#define B_SZ    1024
#define NX      8
#define HID     64

typedef float v2f __attribute__((ext_vector_type(2)));

// d = a*b + c
__device__ __forceinline__ v2f pk_fma(v2f a, v2f b, v2f c) {
  v2f d;
  asm("v_pk_fma_f32 %0, %1, %2, %3" : "=v"(d) : "v"(a), "v"(b), "v"(c));
  return d;
}
// acc += a*b
__device__ __forceinline__ void pk_fma_acc(v2f& acc, v2f a, v2f b) {
  asm("v_pk_fma_f32 %0, %1, %2, %0" : "+v"(acc) : "v"(a), "v"(b));
}
// d = splat_lo(a)*b + c   (a.lo feeds both halves)
__device__ __forceinline__ v2f pk_fma_s0lo(v2f a, v2f b, v2f c) {
  v2f d;
  asm("v_pk_fma_f32 %0, %1, %2, %3 op_sel:[0,0,0] op_sel_hi:[0,1,1]"
      : "=v"(d) : "v"(a), "v"(b), "v"(c));
  return d;
}
// d = splat_hi(a)*b + c   (a.hi feeds both halves)
__device__ __forceinline__ v2f pk_fma_s0hi(v2f a, v2f b, v2f c) {
  v2f d;
  asm("v_pk_fma_f32 %0, %1, %2, %3 op_sel:[1,0,0] op_sel_hi:[1,1,1]"
      : "=v"(d) : "v"(a), "v"(b), "v"(c));
  return d;
}
// acc += a*splat_lo(b)
__device__ __forceinline__ void pk_fma_acc_s1lo(v2f& acc, v2f a, v2f b) {
  asm("v_pk_fma_f32 %0, %1, %2, %0 op_sel:[0,0,0] op_sel_hi:[1,0,1]"
      : "+v"(acc) : "v"(a), "v"(b));
}
// acc += a*splat_hi(b)
__device__ __forceinline__ void pk_fma_acc_s1hi(v2f& acc, v2f a, v2f b) {
  asm("v_pk_fma_f32 %0, %1, %2, %0 op_sel:[0,1,0] op_sel_hi:[1,1,1]"
      : "+v"(acc) : "v"(a), "v"(b));
}

// tanh pair: inputs pre-scaled by 2*log2(e); returns {tanh(a), tanh(b)}
__device__ __forceinline__ v2f tanh_pair(float pa, float pb) {
  v2f r;
  r[0] = __builtin_amdgcn_rcpf(__builtin_amdgcn_exp2f(pa) + 1.0f);
  r[1] = __builtin_amdgcn_rcpf(__builtin_amdgcn_exp2f(pb) + 1.0f);
  v2f h;
  h[0] = fmaf(-2.0f, r[0], 1.0f);
  h[1] = fmaf(-2.0f, r[1], 1.0f);
  return h;
}

template <int CTRL, int RMASK>
__device__ __forceinline__ float dpp_add(float acc) {
  int moved = __builtin_amdgcn_update_dpp(0, __float_as_int(acc), CTRL, RMASK, 0xf, true);
  return acc + __int_as_float(moved);
}

// after this, lane 31 = sum(lanes 0..31), lane 63 = sum(lanes 32..63)
__device__ __forceinline__ float half_reduce(float c) {
  c = dpp_add<0x111, 0xf>(c);  // row_shr:1
  c = dpp_add<0x112, 0xf>(c);  // row_shr:2
  c = dpp_add<0x114, 0xf>(c);  // row_shr:4
  c = dpp_add<0x118, 0xf>(c);  // row_shr:8
  c = dpp_add<0x142, 0xa>(c);  // row_bcast:15 into rows 1,3
  return c;
}

__device__ __forceinline__ void swap32(float& a, float& b) {
  asm("v_permlane32_swap_b32 %0, %1" : "+v"(a), "+v"(b));
}

__device__ __forceinline__ float rlf(float v, int lane) {
  return __int_as_float(__builtin_amdgcn_readlane(__float_as_int(v), lane));
}

__global__ __launch_bounds__(64, 1) void luen_kernel(
    const float* __restrict__ u, const float* __restrict__ y,
    const float* __restrict__ Wf1, const float* __restrict__ bf1,
    const float* __restrict__ Wf2, const float* __restrict__ bf2,
    const float* __restrict__ Wg, const float* __restrict__ bg,
    const float* __restrict__ Wk1, const float* __restrict__ bk1,
    const float* __restrict__ Wk2, const float* __restrict__ bk2,
    float* __restrict__ out) {
  const int eb = blockIdx.x;
  const int h  = threadIdx.x;

  const float TS = 2.885390081777927f;  // 2*log2(e)
  const float INV64 = 1.0f / 64.0f;

  // ---- per-lane weight columns (canonical order) ----
  v2f wf1p[5];
#pragma unroll
  for (int p = 0; p < 5; ++p)
    wf1p[p] = v2f{TS * Wf1[(2 * p) * HID + h], TS * Wf1[(2 * p + 1) * HID + h]};
  v2f wk1p[4];
#pragma unroll
  for (int p = 0; p < 4; ++p)
    wk1p[p] = v2f{TS * Wk1[(2 * p) * HID + h], TS * Wk1[(2 * p + 1) * HID + h]};

  v2f wf2p[4], bf2sp[4];
#pragma unroll
  for (int p = 0; p < 4; ++p) {
    wf2p[p]  = v2f{Wf2[h * NX + 2 * p], Wf2[h * NX + 2 * p + 1]};
    bf2sp[p] = v2f{INV64 * bf2[2 * p], INV64 * bf2[2 * p + 1]};
  }
  v2f wk2e[4], wk2o[4], bk2se[4], bk2so[4];
#pragma unroll
  for (int p = 0; p < 4; ++p) {
    const float* r = Wk2 + h * (NX * 2);
    wk2e[p]  = v2f{r[4 * p], r[4 * p + 2]};
    wk2o[p]  = v2f{r[4 * p + 1], r[4 * p + 3]};
    bk2se[p] = v2f{INV64 * bk2[4 * p], INV64 * bk2[4 * p + 2]};
    bk2so[p] = v2f{INV64 * bk2[4 * p + 1], INV64 * bk2[4 * p + 3]};
  }
  v2f wgc0[4], wgc1[4];
#pragma unroll
  for (int p = 0; p < 4; ++p) {
    wgc0[p] = v2f{Wg[4 * p], Wg[4 * p + 2]};
    wgc1[p] = v2f{Wg[4 * p + 1], Wg[4 * p + 3]};
  }
  const v2f a0i = v2f{bg[0], 0.0f};
  const v2f a1i = v2f{bg[1], 0.0f};
  const v2f pfi = v2f{TS * bf1[h], 0.0f};
  const v2f pki = v2f{TS * bk1[h], 0.0f};

  // ---- permlane32_swap direction probe (one-time; proven R3/R6) ----
  float probe = (h < 32) ? 0.0f : 1.0f;
  float zf = 0.0f;
  swap32(probe, zf);
  const bool dir1 = __builtin_amdgcn_readlane(__float_as_int(probe), 32) != 0;
  const int laneA = dir1 ? 63 : 31;  // sum of c[j]
  const int laneB = dir1 ? 31 : 63;  // sum of c[j+4]

  const v2f* __restrict__ pu = reinterpret_cast<const v2f*>(u) + eb;
  const v2f* __restrict__ py = reinterpret_cast<const v2f*>(y) + eb;
  const int STR = B_SZ;

  v2f x2[4];
#pragma unroll
  for (int p = 0; p < 4; ++p) x2[p] = v2f{0.0f, 0.0f};

  v2f Au[4], Ay[4], Bu[4], By[4];

#define LOADG(SET_u, SET_y)                          \
  {                                                  \
    SET_u[0] = pu[0 * STR]; SET_u[1] = pu[1 * STR];  \
    SET_u[2] = pu[2 * STR]; SET_u[3] = pu[3 * STR];  \
    SET_y[0] = py[0 * STR]; SET_y[1] = py[1 * STR];  \
    SET_y[2] = py[2 * STR]; SET_y[3] = py[3 * STR];  \
    pu += 4 * STR; py += 4 * STR;                    \
  }

#define STEP(CU_, CY_)                                                        \
  {                                                                           \
    const v2f cu = (CU_);                                                     \
    const v2f cy = (CY_);                                                     \
    /* y_hat and packed error ep = {e0, e1} */                                \
    v2f a0 = pk_fma(x2[0], wgc0[0], a0i);                                     \
    v2f a1 = pk_fma(x2[0], wgc1[0], a1i);                                     \
    pk_fma_acc(a0, x2[1], wgc0[1]); pk_fma_acc(a1, x2[1], wgc1[1]);           \
    pk_fma_acc(a0, x2[2], wgc0[2]); pk_fma_acc(a1, x2[2], wgc1[2]);           \
    pk_fma_acc(a0, x2[3], wgc0[3]); pk_fma_acc(a1, x2[3], wgc1[3]);           \
    v2f ep;                                                                   \
    ep[0] = a0[0] + a0[1] - cy[0];                                            \
    ep[1] = a1[0] + a1[1] - cy[1];                                            \
    /* f-net / k-net pre-activations -> packed hp = {h1, h2} */               \
    v2f pf = pk_fma(x2[0], wf1p[0], pfi);                                     \
    pk_fma_acc(pf, x2[1], wf1p[1]);                                           \
    pk_fma_acc(pf, x2[2], wf1p[2]);                                           \
    pk_fma_acc(pf, x2[3], wf1p[3]);                                           \
    pk_fma_acc(pf, cu, wf1p[4]);                                              \
    v2f pkv = pk_fma(x2[0], wk1p[0], pki);                                    \
    pk_fma_acc(pkv, x2[1], wk1p[1]);                                          \
    pk_fma_acc(pkv, x2[2], wk1p[2]);                                          \
    pk_fma_acc(pkv, x2[3], wk1p[3]);                                          \
    const v2f hp = tanh_pair(pf[0] + pf[1], pkv[0] + pkv[1]);                 \
    /* per-lane contributions: op_sel splats (PROVEN R6) */                   \
    float c0, c1, c2, c3, c4, c5, c6, c7;                                     \
    {                                                                         \
      v2f t0 = pk_fma_s0hi(hp, wk2e[0], bk2se[0]);                            \
      v2f t1 = pk_fma_s0hi(hp, wk2o[0], bk2so[0]);                            \
      v2f cp = pk_fma_s0lo(hp, wf2p[0], bf2sp[0]);                            \
      pk_fma_acc_s1lo(cp, t0, ep);                                            \
      pk_fma_acc_s1hi(cp, t1, ep);                                            \
      c0 = cp[0]; c1 = cp[1];                                                 \
    }                                                                         \
    {                                                                         \
      v2f t0 = pk_fma_s0hi(hp, wk2e[1], bk2se[1]);                            \
      v2f t1 = pk_fma_s0hi(hp, wk2o[1], bk2so[1]);                            \
      v2f cp = pk_fma_s0lo(hp, wf2p[1], bf2sp[1]);                            \
      pk_fma_acc_s1lo(cp, t0, ep);                                            \
      pk_fma_acc_s1hi(cp, t1, ep);                                            \
      c2 = cp[0]; c3 = cp[1];                                                 \
    }                                                                         \
    {                                                                         \
      v2f t0 = pk_fma_s0hi(hp, wk2e[2], bk2se[2]);                            \
      v2f t1 = pk_fma_s0hi(hp, wk2o[2], bk2so[2]);                            \
      v2f cp = pk_fma_s0lo(hp, wf2p[2], bf2sp[2]);                            \
      pk_fma_acc_s1lo(cp, t0, ep);                                            \
      pk_fma_acc_s1hi(cp, t1, ep);                                            \
      c4 = cp[0]; c5 = cp[1];                                                 \
    }                                                                         \
    {                                                                         \
      v2f t0 = pk_fma_s0hi(hp, wk2e[3], bk2se[3]);                            \
      v2f t1 = pk_fma_s0hi(hp, wk2o[3], bk2so[3]);                            \
      v2f cp = pk_fma_s0lo(hp, wf2p[3], bf2sp[3]);                            \
      pk_fma_acc_s1lo(cp, t0, ep);                                            \
      pk_fma_acc_s1hi(cp, t1, ep);                                            \
      c6 = cp[0]; c7 = cp[1];                                                 \
    }                                                                         \
    /* PROVEN reduction: swap32 fold + 5-stage half-reduce */                 \
    swap32(c0, c4); float d0 = c0 + c4;                                       \
    swap32(c1, c5); float d1 = c1 + c5;                                       \
    swap32(c2, c6); float d2 = c2 + c6;                                       \
    swap32(c3, c7); float d3 = c3 + c7;                                       \
    d0 = half_reduce(d0); d1 = half_reduce(d1);                               \
    d2 = half_reduce(d2); d3 = half_reduce(d3);                               \
    x2[0][0] += rlf(d0, laneA);                                               \
    x2[0][1] += rlf(d1, laneA);                                               \
    x2[1][0] += rlf(d2, laneA);                                               \
    x2[1][1] += rlf(d3, laneA);                                               \
    x2[2][0] += rlf(d0, laneB);                                               \
    x2[2][1] += rlf(d1, laneB);                                               \
    x2[3][0] += rlf(d2, laneB);                                               \
    x2[3][1] += rlf(d3, laneB);                                               \
  }

  LOADG(Au, Ay);
  LOADG(Bu, By);

  for (int it = 0; it < 255; ++it) {
    STEP(Au[0], Ay[0]); STEP(Au[1], Ay[1]); STEP(Au[2], Ay[2]); STEP(Au[3], Ay[3]);
    LOADG(Au, Ay);
    STEP(Bu[0], By[0]); STEP(Bu[1], By[1]); STEP(Bu[2], By[2]); STEP(Bu[3], By[3]);
    LOADG(Bu, By);
  }
  STEP(Au[0], Ay[0]); STEP(Au[1], Ay[1]); STEP(Au[2], Ay[2]); STEP(Au[3], Ay[3]);
  STEP(Bu[0], By[0]); STEP(Bu[1], By[1]); STEP(Bu[2], By[2]); STEP(Bu[3], By[3]);
#undef STEP
#undef LOADG

  if (h == 0) {
#pragma unroll
    for (int p = 0; p < 4; ++p) {
      out[eb * NX + 2 * p]     = x2[p][0];
      out[eb * NX + 2 * p + 1] = x2[p][1];
    }
  }
}

extern "C" void kernel_launch(void* const* d_in, const int* in_sizes, int n_in,
                              void* d_out, int out_size, void* d_ws, size_t ws_size,
                              hipStream_t stream) {
  const float* u   = (const float*)d_in[0];
  const float* y   = (const float*)d_in[1];
  const float* Wf1 = (const float*)d_in[2];
  const float* bf1 = (const float*)d_in[3];
  const float* Wf2 = (const float*)d_in[4];
  const float* bf2 = (const float*)d_in[5];
  const float* Wg  = (const float*)d_in[6];
  const float* bg  = (const float*)d_in[7];
  const float* Wk1 = (const float*)d_in[8];
  const float* bk1 = (const float*)d_in[9];
  const float* Wk2 = (const float*)d_in[10];
  const float* bk2 = (const float*)d_in[11];

  luen_kernel<<<dim3(B_SZ), dim3(HID), 0, stream>>>(
      u, y, Wf1, bf1, Wf2, bf2, Wg, bg, Wk1, bk1, Wk2, bk2, (float*)d_out);
}

// Round 12
// 589.735 us; speedup vs baseline: 2.0784x; 1.1288x over previous
//
#include <hip/hip_runtime.h>

// Luenberger state estimator: T=2048 sequential steps, B=1024 independent
// elements. 1 wave/element (1024 blocks x 64 threads), lane h = hidden unit h
// of BOTH MLPs. R12 = R11 (proven 664us) + validated two-level fold:
//  - swap32 fold (proven) then permlane16_swap fold + 4-stage builtin-DPP
//    prefix on 2 regs. Slot->source mapping discovered by a per-half
//    power-of-2 marker probe run through the EXACT fast-path pipeline;
//    decode requires exact, bijective 32*2^j -> any row-mixing or unknown
//    semantics trips the wave-uniform fallback to the exact R11 reduce.
//  - ALL DPP via __builtin_amdgcn_update_dpp (compiler inserts hazard nops;
//    R10's raw-asm v_add_f32_dpp violated VALU->DPP wait states -> garbage
//    in BOTH paths, which is why swap16 was never cleanly tested until now).
//  - permlane{16,32}_swap via inline asm: same instr class as swap32, which
//    has been proven since R3.

#define T_STEPS 2048
#define B_SZ    1024
#define NX      8
#define HID     64

typedef float v2f __attribute__((ext_vector_type(2)));

// d = a*b + c
__device__ __forceinline__ v2f pk_fma(v2f a, v2f b, v2f c) {
  v2f d;
  asm("v_pk_fma_f32 %0, %1, %2, %3" : "=v"(d) : "v"(a), "v"(b), "v"(c));
  return d;
}
// acc += a*b
__device__ __forceinline__ void pk_fma_acc(v2f& acc, v2f a, v2f b) {
  asm("v_pk_fma_f32 %0, %1, %2, %0" : "+v"(acc) : "v"(a), "v"(b));
}
// d = splat_lo(a)*b + c   (PROVEN R6)
__device__ __forceinline__ v2f pk_fma_s0lo(v2f a, v2f b, v2f c) {
  v2f d;
  asm("v_pk_fma_f32 %0, %1, %2, %3 op_sel:[0,0,0] op_sel_hi:[0,1,1]"
      : "=v"(d) : "v"(a), "v"(b), "v"(c));
  return d;
}
// d = splat_hi(a)*b + c   (PROVEN R6)
__device__ __forceinline__ v2f pk_fma_s0hi(v2f a, v2f b, v2f c) {
  v2f d;
  asm("v_pk_fma_f32 %0, %1, %2, %3 op_sel:[1,0,0] op_sel_hi:[1,1,1]"
      : "=v"(d) : "v"(a), "v"(b), "v"(c));
  return d;
}
// acc += a*splat_lo(b)    (PROVEN R6)
__device__ __forceinline__ void pk_fma_acc_s1lo(v2f& acc, v2f a, v2f b) {
  asm("v_pk_fma_f32 %0, %1, %2, %0 op_sel:[0,0,0] op_sel_hi:[1,0,1]"
      : "+v"(acc) : "v"(a), "v"(b));
}
// acc += a*splat_hi(b)    (PROVEN R6)
__device__ __forceinline__ void pk_fma_acc_s1hi(v2f& acc, v2f a, v2f b) {
  asm("v_pk_fma_f32 %0, %1, %2, %0 op_sel:[0,1,0] op_sel_hi:[1,1,1]"
      : "+v"(acc) : "v"(a), "v"(b));
}

// tanh pair: inputs pre-scaled by 2*log2(e); returns {tanh(a), tanh(b)}
__device__ __forceinline__ v2f tanh_pair(float pa, float pb) {
  v2f r;
  r[0] = __builtin_amdgcn_rcpf(__builtin_amdgcn_exp2f(pa) + 1.0f);
  r[1] = __builtin_amdgcn_rcpf(__builtin_amdgcn_exp2f(pb) + 1.0f);
  v2f h;
  h[0] = fmaf(-2.0f, r[0], 1.0f);
  h[1] = fmaf(-2.0f, r[1], 1.0f);
  return h;
}

template <int CTRL, int RMASK>
__device__ __forceinline__ float dpp_add(float acc) {
  int moved = __builtin_amdgcn_update_dpp(0, __float_as_int(acc), CTRL, RMASK, 0xf, true);
  return acc + __int_as_float(moved);
}

// 4-stage row prefix (builtin DPP): lanes {15,31,47,63} end with their row sum
__device__ __forceinline__ float prefix16(float c) {
  c = dpp_add<0x111, 0xf>(c);  // row_shr:1
  c = dpp_add<0x112, 0xf>(c);  // row_shr:2
  c = dpp_add<0x114, 0xf>(c);  // row_shr:4
  c = dpp_add<0x118, 0xf>(c);  // row_shr:8
  return c;
}
// 5-stage: lane 31 = sum(0..31), lane 63 = sum(32..63)  (PROVEN R3/R6/R11)
__device__ __forceinline__ float half_reduce(float c) {
  c = prefix16(c);
  c = dpp_add<0x142, 0xa>(c);  // row_bcast:15 into rows 1,3
  return c;
}

__device__ __forceinline__ void swap32(float& a, float& b) {
  asm("v_permlane32_swap_b32 %0, %1" : "+v"(a), "+v"(b));
}
__device__ __forceinline__ void swap16(float& a, float& b) {
  asm("v_permlane16_swap_b32 %0, %1" : "+v"(a), "+v"(b));
}

__device__ __forceinline__ float rlf(float v, int lane) {
  return __int_as_float(__builtin_amdgcn_readlane(__float_as_int(v), lane));
}

__global__ __launch_bounds__(64, 1) void luen_kernel(
    const float* __restrict__ u, const float* __restrict__ y,
    const float* __restrict__ Wf1, const float* __restrict__ bf1,
    const float* __restrict__ Wf2, const float* __restrict__ bf2,
    const float* __restrict__ Wg, const float* __restrict__ bg,
    const float* __restrict__ Wk1, const float* __restrict__ bk1,
    const float* __restrict__ Wk2, const float* __restrict__ bk2,
    float* __restrict__ out) {
  const int eb = blockIdx.x;
  const int h  = threadIdx.x;

  const float TS = 2.885390081777927f;  // 2*log2(e)
  const float INV64 = 1.0f / 64.0f;

  // ---- permlane32_swap direction probe (non-uniform; PROVEN R3/R6) ----
  float probe = (h < 32) ? 0.0f : 1.0f;
  float zf = 0.0f;
  swap32(probe, zf);
  const bool dir1 = __builtin_amdgcn_readlane(__float_as_int(probe), 32) != 0;
  const int laneA = dir1 ? 63 : 31;  // sum of c[j]   (fallback path)
  const int laneB = dir1 ? 31 : 63;  // sum of c[j+4] (fallback path)

  // ---- swap16 mapping probe, per-half power-of-2 markers (R10 design,
  //      now with hazard-safe builtin-DPP prefix16) ----
  int kof[8];
  bool fastok;
  {
    float dP[4];
#pragma unroll
    for (int j = 0; j < 4; ++j) {
      // replicate post-swap32-fold state: laneA-half carries c_j,
      // other half carries c_{j+4}
      const float hiM = dir1 ? (float)(1 << j) : (float)(1 << (j + 4));
      const float loM = dir1 ? (float)(1 << (j + 4)) : (float)(1 << j);
      dP[j] = (h < 32) ? loM : hiM;
    }
    swap16(dP[0], dP[1]); float ffP = dP[0] + dP[1];
    swap16(dP[2], dP[3]); float ggP = dP[2] + dP[3];
    ffP = prefix16(ffP);
    ggP = prefix16(ggP);
    float sv[8];
    sv[0] = rlf(ffP, 15); sv[1] = rlf(ffP, 31);
    sv[2] = rlf(ffP, 47); sv[3] = rlf(ffP, 63);
    sv[4] = rlf(ggP, 15); sv[5] = rlf(ggP, 31);
    sv[6] = rlf(ggP, 47); sv[7] = rlf(ggP, 63);
    int jm[8];
    fastok = true;
    int seen = 0;
#pragma unroll
    for (int s = 0; s < 8; ++s) {
      const float r = sv[s] * 0.03125f;      // /32; each slot must be 32*2^j
      const int iv = (int)r;
      const bool ok = ((float)iv == r) && iv > 0 && iv <= 128 &&
                      ((iv & (iv - 1)) == 0);
      const int j = ok ? __builtin_ctz(iv) : 0;
      jm[s] = j;
      seen |= ok ? (1 << j) : 0;
      fastok = fastok && ok;
    }
    fastok = fastok && (seen == 0xFF);       // bijective
#pragma unroll
    for (int j = 0; j < 8; ++j) {
      if (fastok) {
        int v = 0;
#pragma unroll
        for (int s = 0; s < 8; ++s) v += (jm[s] == j) ? s : 0;
        kof[j] = v;                          // kof = jm^{-1}
      } else {
        kof[j] = j;                          // identity for fallback path
      }
    }
  }

  // ---- per-lane weight columns (input side: canonical order) ----
  v2f wf1p[5];
#pragma unroll
  for (int p = 0; p < 5; ++p)
    wf1p[p] = v2f{TS * Wf1[(2 * p) * HID + h], TS * Wf1[(2 * p + 1) * HID + h]};
  v2f wk1p[4];
#pragma unroll
  for (int p = 0; p < 4; ++p)
    wk1p[p] = v2f{TS * Wk1[(2 * p) * HID + h], TS * Wk1[(2 * p + 1) * HID + h]};

  // ---- output side: permuted by kof (identity when fallback) ----
  v2f wf2p[4], bf2sp[4], wk2e[4], wk2o[4], bk2se[4], bk2so[4];
  {
    const float* wf2row = Wf2 + h * NX;
    const float* wk2row = Wk2 + h * (NX * 2);
#pragma unroll
    for (int p = 0; p < 4; ++p) {
      const int kl = kof[2 * p], kh = kof[2 * p + 1];
      wf2p[p]  = v2f{wf2row[kl], wf2row[kh]};
      bf2sp[p] = v2f{INV64 * bf2[kl], INV64 * bf2[kh]};
      wk2e[p]  = v2f{wk2row[2 * kl], wk2row[2 * kh]};
      wk2o[p]  = v2f{wk2row[2 * kl + 1], wk2row[2 * kh + 1]};
      bk2se[p] = v2f{INV64 * bk2[2 * kl], INV64 * bk2[2 * kh]};
      bk2so[p] = v2f{INV64 * bk2[2 * kl + 1], INV64 * bk2[2 * kh + 1]};
    }
  }
  v2f wgc0[4], wgc1[4];
#pragma unroll
  for (int p = 0; p < 4; ++p) {
    wgc0[p] = v2f{Wg[4 * p], Wg[4 * p + 2]};
    wgc1[p] = v2f{Wg[4 * p + 1], Wg[4 * p + 3]};
  }
  const v2f a0i = v2f{bg[0], 0.0f};
  const v2f a1i = v2f{bg[1], 0.0f};
  const v2f pfi = v2f{TS * bf1[h], 0.0f};
  const v2f pki = v2f{TS * bk1[h], 0.0f};

  const v2f* __restrict__ pu = reinterpret_cast<const v2f*>(u) + eb;
  const v2f* __restrict__ py = reinterpret_cast<const v2f*>(y) + eb;
  const int STR = B_SZ;

  v2f x2[4];
#pragma unroll
  for (int p = 0; p < 4; ++p) x2[p] = v2f{0.0f, 0.0f};

  v2f Au[4], Ay[4], Bu[4], By[4];

#define LOADG(SET_u, SET_y)                          \
  {                                                  \
    SET_u[0] = pu[0 * STR]; SET_u[1] = pu[1 * STR];  \
    SET_u[2] = pu[2 * STR]; SET_u[3] = pu[3 * STR];  \
    SET_y[0] = py[0 * STR]; SET_y[1] = py[1 * STR];  \
    SET_y[2] = py[2 * STR]; SET_y[3] = py[3 * STR];  \
    pu += 4 * STR; py += 4 * STR;                    \
  }

#define STEP(CU_, CY_)                                                        \
  {                                                                           \
    const v2f cu = (CU_);                                                     \
    const v2f cy = (CY_);                                                     \
    /* y_hat and packed error ep = {e0, e1} */                                \
    v2f a0 = pk_fma(x2[0], wgc0[0], a0i);                                     \
    v2f a1 = pk_fma(x2[0], wgc1[0], a1i);                                     \
    pk_fma_acc(a0, x2[1], wgc0[1]); pk_fma_acc(a1, x2[1], wgc1[1]);           \
    pk_fma_acc(a0, x2[2], wgc0[2]); pk_fma_acc(a1, x2[2], wgc1[2]);           \
    pk_fma_acc(a0, x2[3], wgc0[3]); pk_fma_acc(a1, x2[3], wgc1[3]);           \
    v2f ep;                                                                   \
    ep[0] = a0[0] + a0[1] - cy[0];                                            \
    ep[1] = a1[0] + a1[1] - cy[1];                                            \
    /* f-net / k-net pre-activations -> packed hp = {h1, h2} */               \
    v2f pf = pk_fma(x2[0], wf1p[0], pfi);                                     \
    pk_fma_acc(pf, x2[1], wf1p[1]);                                           \
    pk_fma_acc(pf, x2[2], wf1p[2]);                                           \
    pk_fma_acc(pf, x2[3], wf1p[3]);                                           \
    pk_fma_acc(pf, cu, wf1p[4]);                                              \
    v2f pkv = pk_fma(x2[0], wk1p[0], pki);                                    \
    pk_fma_acc(pkv, x2[1], wk1p[1]);                                          \
    pk_fma_acc(pkv, x2[2], wk1p[2]);                                          \
    pk_fma_acc(pkv, x2[3], wk1p[3]);                                          \
    const v2f hp = tanh_pair(pf[0] + pf[1], pkv[0] + pkv[1]);                 \
    /* per-lane contributions: op_sel splats (PROVEN R6) */                   \
    float c0, c1, c2, c3, c4, c5, c6, c7;                                     \
    {                                                                         \
      v2f t0 = pk_fma_s0hi(hp, wk2e[0], bk2se[0]);                            \
      v2f t1 = pk_fma_s0hi(hp, wk2o[0], bk2so[0]);                            \
      v2f cp = pk_fma_s0lo(hp, wf2p[0], bf2sp[0]);                            \
      pk_fma_acc_s1lo(cp, t0, ep);                                            \
      pk_fma_acc_s1hi(cp, t1, ep);                                            \
      c0 = cp[0]; c1 = cp[1];                                                 \
    }                                                                         \
    {                                                                         \
      v2f t0 = pk_fma_s0hi(hp, wk2e[1], bk2se[1]);                            \
      v2f t1 = pk_fma_s0hi(hp, wk2o[1], bk2so[1]);                            \
      v2f cp = pk_fma_s0lo(hp, wf2p[1], bf2sp[1]);                            \
      pk_fma_acc_s1lo(cp, t0, ep);                                            \
      pk_fma_acc_s1hi(cp, t1, ep);                                            \
      c2 = cp[0]; c3 = cp[1];                                                 \
    }                                                                         \
    {                                                                         \
      v2f t0 = pk_fma_s0hi(hp, wk2e[2], bk2se[2]);                            \
      v2f t1 = pk_fma_s0hi(hp, wk2o[2], bk2so[2]);                            \
      v2f cp = pk_fma_s0lo(hp, wf2p[2], bf2sp[2]);                            \
      pk_fma_acc_s1lo(cp, t0, ep);                                            \
      pk_fma_acc_s1hi(cp, t1, ep);                                            \
      c4 = cp[0]; c5 = cp[1];                                                 \
    }                                                                         \
    {                                                                         \
      v2f t0 = pk_fma_s0hi(hp, wk2e[3], bk2se[3]);                            \
      v2f t1 = pk_fma_s0hi(hp, wk2o[3], bk2so[3]);                            \
      v2f cp = pk_fma_s0lo(hp, wf2p[3], bf2sp[3]);                            \
      pk_fma_acc_s1lo(cp, t0, ep);                                            \
      pk_fma_acc_s1hi(cp, t1, ep);                                            \
      c6 = cp[0]; c7 = cp[1];                                                 \
    }                                                                         \
    /* PROVEN swap32 fold */                                                  \
    swap32(c0, c4); float d0 = c0 + c4;                                       \
    swap32(c1, c5); float d1 = c1 + c5;                                       \
    swap32(c2, c6); float d2 = c2 + c6;                                       \
    swap32(c3, c7); float d3 = c3 + c7;                                       \
    if (fastok) {                                                             \
      /* two-level: swap16 fold + 4-stage builtin-DPP prefix */               \
      swap16(d0, d1); float ff = d0 + d1;                                     \
      swap16(d2, d3); float gg = d2 + d3;                                     \
      ff = prefix16(ff);                                                      \
      gg = prefix16(gg);                                                      \
      x2[0][0] += rlf(ff, 15); x2[0][1] += rlf(ff, 31);                       \
      x2[1][0] += rlf(ff, 47); x2[1][1] += rlf(ff, 63);                       \
      x2[2][0] += rlf(gg, 15); x2[2][1] += rlf(gg, 31);                       \
      x2[3][0] += rlf(gg, 47); x2[3][1] += rlf(gg, 63);                       \
    } else {                                                                  \
      /* exact R11 path (kof == identity) */                                  \
      d0 = half_reduce(d0); d1 = half_reduce(d1);                             \
      d2 = half_reduce(d2); d3 = half_reduce(d3);                             \
      x2[0][0] += rlf(d0, laneA); x2[0][1] += rlf(d1, laneA);                 \
      x2[1][0] += rlf(d2, laneA); x2[1][1] += rlf(d3, laneA);                 \
      x2[2][0] += rlf(d0, laneB); x2[2][1] += rlf(d1, laneB);                 \
      x2[3][0] += rlf(d2, laneB); x2[3][1] += rlf(d3, laneB);                 \
    }                                                                         \
  }

  LOADG(Au, Ay);
  LOADG(Bu, By);

  for (int it = 0; it < 255; ++it) {
    STEP(Au[0], Ay[0]); STEP(Au[1], Ay[1]); STEP(Au[2], Ay[2]); STEP(Au[3], Ay[3]);
    LOADG(Au, Ay);
    STEP(Bu[0], By[0]); STEP(Bu[1], By[1]); STEP(Bu[2], By[2]); STEP(Bu[3], By[3]);
    LOADG(Bu, By);
  }
  STEP(Au[0], Ay[0]); STEP(Au[1], Ay[1]); STEP(Au[2], Ay[2]); STEP(Au[3], Ay[3]);
  STEP(Bu[0], By[0]); STEP(Bu[1], By[1]); STEP(Bu[2], By[2]); STEP(Bu[3], By[3]);
#undef STEP
#undef LOADG

  if (h == 0) {
#pragma unroll
    for (int p = 0; p < 4; ++p) {
      out[eb * NX + 2 * p]     = x2[p][0];
      out[eb * NX + 2 * p + 1] = x2[p][1];
    }
  }
}

extern "C" void kernel_launch(void* const* d_in, const int* in_sizes, int n_in,
                              void* d_out, int out_size, void* d_ws, size_t ws_size,
                              hipStream_t stream) {
  const float* u   = (const float*)d_in[0];
  const float* y   = (const float*)d_in[1];
  const float* Wf1 = (const float*)d_in[2];
  const float* bf1 = (const float*)d_in[3];
  const float* Wf2 = (const float*)d_in[4];
  const float* bf2 = (const float*)d_in[5];
  const float* Wg  = (const float*)d_in[6];
  const float* bg  = (const float*)d_in[7];
  const float* Wk1 = (const float*)d_in[8];
  const float* bk1 = (const float*)d_in[9];
  const float* Wk2 = (const float*)d_in[10];
  const float* bk2 = (const float*)d_in[11];

  luen_kernel<<<dim3(B_SZ), dim3(HID), 0, stream>>>(
      u, y, Wf1, bf1, Wf2, bf2, Wg, bg, Wk1, bk1, Wk2, bk2, (float*)d_out);
}

// Round 13
// 577.338 us; speedup vs baseline: 2.1230x; 1.0215x over previous
//
#include <hip/hip_runtime.h>

// Luenberger state estimator: T=2048 sequential steps, B=1024 independent
// elements. 1 wave/element (1024 blocks x 64 threads), lane h = hidden unit h
// of BOTH MLPs. R13 = R12 (proven 590us) + splat-x dot restructuring:
//  - packed yhat: ya = sum_k splat(x[k])*{Wg[k][0],Wg[k][1]} (8 op_sel fma)
//    + 2 scalar subs -> ep. Eliminates 2 horizontal adds.
//  - fused f/k prenet: pre = sum_k splat(x[k])*{TSWf1[k][h],TSWk1[k][h]}
//    (8 op_sel fma) + 2 scalar fmaf u-terms into pre.lo -> tanh_pair direct.
//    Eliminates 2 horizontal adds, fuses two chains into one.
//  - reduce (swap32+swap16 folds, validated probe, kof-permuted output
//    weights, builtin-DPP prefix) byte-identical to R12. Fallback intact.
// All op_sel encodings are the R6-proven forms (s0lo/s0hi/s1lo/s1hi).

#define T_STEPS 2048
#define B_SZ    1024
#define NX      8
#define HID     64

typedef float v2f __attribute__((ext_vector_type(2)));

// d = a*b + c
__device__ __forceinline__ v2f pk_fma(v2f a, v2f b, v2f c) {
  v2f d;
  asm("v_pk_fma_f32 %0, %1, %2, %3" : "=v"(d) : "v"(a), "v"(b), "v"(c));
  return d;
}
// acc += a*b
__device__ __forceinline__ void pk_fma_acc(v2f& acc, v2f a, v2f b) {
  asm("v_pk_fma_f32 %0, %1, %2, %0" : "+v"(acc) : "v"(a), "v"(b));
}
// d = splat_lo(a)*b + c   (PROVEN R6)
__device__ __forceinline__ v2f pk_fma_s0lo(v2f a, v2f b, v2f c) {
  v2f d;
  asm("v_pk_fma_f32 %0, %1, %2, %3 op_sel:[0,0,0] op_sel_hi:[0,1,1]"
      : "=v"(d) : "v"(a), "v"(b), "v"(c));
  return d;
}
// d = splat_hi(a)*b + c   (PROVEN R6)
__device__ __forceinline__ v2f pk_fma_s0hi(v2f a, v2f b, v2f c) {
  v2f d;
  asm("v_pk_fma_f32 %0, %1, %2, %3 op_sel:[1,0,0] op_sel_hi:[1,1,1]"
      : "=v"(d) : "v"(a), "v"(b), "v"(c));
  return d;
}
// acc += a*splat_lo(b)    (PROVEN R6)
__device__ __forceinline__ void pk_fma_acc_s1lo(v2f& acc, v2f a, v2f b) {
  asm("v_pk_fma_f32 %0, %1, %2, %0 op_sel:[0,0,0] op_sel_hi:[1,0,1]"
      : "+v"(acc) : "v"(a), "v"(b));
}
// acc += a*splat_hi(b)    (PROVEN R6)
__device__ __forceinline__ void pk_fma_acc_s1hi(v2f& acc, v2f a, v2f b) {
  asm("v_pk_fma_f32 %0, %1, %2, %0 op_sel:[0,1,0] op_sel_hi:[1,1,1]"
      : "+v"(acc) : "v"(a), "v"(b));
}

// tanh pair: inputs pre-scaled by 2*log2(e); returns {tanh(a), tanh(b)}
__device__ __forceinline__ v2f tanh_pair(float pa, float pb) {
  v2f r;
  r[0] = __builtin_amdgcn_rcpf(__builtin_amdgcn_exp2f(pa) + 1.0f);
  r[1] = __builtin_amdgcn_rcpf(__builtin_amdgcn_exp2f(pb) + 1.0f);
  v2f h;
  h[0] = fmaf(-2.0f, r[0], 1.0f);
  h[1] = fmaf(-2.0f, r[1], 1.0f);
  return h;
}

template <int CTRL, int RMASK>
__device__ __forceinline__ float dpp_add(float acc) {
  int moved = __builtin_amdgcn_update_dpp(0, __float_as_int(acc), CTRL, RMASK, 0xf, true);
  return acc + __int_as_float(moved);
}

// 4-stage row prefix (builtin DPP): lanes {15,31,47,63} end with their row sum
__device__ __forceinline__ float prefix16(float c) {
  c = dpp_add<0x111, 0xf>(c);  // row_shr:1
  c = dpp_add<0x112, 0xf>(c);  // row_shr:2
  c = dpp_add<0x114, 0xf>(c);  // row_shr:4
  c = dpp_add<0x118, 0xf>(c);  // row_shr:8
  return c;
}
// 5-stage: lane 31 = sum(0..31), lane 63 = sum(32..63)  (PROVEN R3/R6/R11)
__device__ __forceinline__ float half_reduce(float c) {
  c = prefix16(c);
  c = dpp_add<0x142, 0xa>(c);  // row_bcast:15 into rows 1,3
  return c;
}

__device__ __forceinline__ void swap32(float& a, float& b) {
  asm("v_permlane32_swap_b32 %0, %1" : "+v"(a), "+v"(b));
}
__device__ __forceinline__ void swap16(float& a, float& b) {
  asm("v_permlane16_swap_b32 %0, %1" : "+v"(a), "+v"(b));
}

__device__ __forceinline__ float rlf(float v, int lane) {
  return __int_as_float(__builtin_amdgcn_readlane(__float_as_int(v), lane));
}

__global__ __launch_bounds__(64, 1) void luen_kernel(
    const float* __restrict__ u, const float* __restrict__ y,
    const float* __restrict__ Wf1, const float* __restrict__ bf1,
    const float* __restrict__ Wf2, const float* __restrict__ bf2,
    const float* __restrict__ Wg, const float* __restrict__ bg,
    const float* __restrict__ Wk1, const float* __restrict__ bk1,
    const float* __restrict__ Wk2, const float* __restrict__ bk2,
    float* __restrict__ out) {
  const int eb = blockIdx.x;
  const int h  = threadIdx.x;

  const float TS = 2.885390081777927f;  // 2*log2(e)
  const float INV64 = 1.0f / 64.0f;

  // ---- permlane32_swap direction probe (non-uniform; PROVEN R3/R6) ----
  float probe = (h < 32) ? 0.0f : 1.0f;
  float zf = 0.0f;
  swap32(probe, zf);
  const bool dir1 = __builtin_amdgcn_readlane(__float_as_int(probe), 32) != 0;
  const int laneA = dir1 ? 63 : 31;  // sum of c[j]   (fallback path)
  const int laneB = dir1 ? 31 : 63;  // sum of c[j+4] (fallback path)

  // ---- swap16 mapping probe, per-half power-of-2 markers (PROVEN R12) ----
  int kof[8];
  bool fastok;
  {
    float dP[4];
#pragma unroll
    for (int j = 0; j < 4; ++j) {
      const float hiM = dir1 ? (float)(1 << j) : (float)(1 << (j + 4));
      const float loM = dir1 ? (float)(1 << (j + 4)) : (float)(1 << j);
      dP[j] = (h < 32) ? loM : hiM;
    }
    swap16(dP[0], dP[1]); float ffP = dP[0] + dP[1];
    swap16(dP[2], dP[3]); float ggP = dP[2] + dP[3];
    ffP = prefix16(ffP);
    ggP = prefix16(ggP);
    float sv[8];
    sv[0] = rlf(ffP, 15); sv[1] = rlf(ffP, 31);
    sv[2] = rlf(ffP, 47); sv[3] = rlf(ffP, 63);
    sv[4] = rlf(ggP, 15); sv[5] = rlf(ggP, 31);
    sv[6] = rlf(ggP, 47); sv[7] = rlf(ggP, 63);
    int jm[8];
    fastok = true;
    int seen = 0;
#pragma unroll
    for (int s = 0; s < 8; ++s) {
      const float r = sv[s] * 0.03125f;      // /32; each slot must be 32*2^j
      const int iv = (int)r;
      const bool ok = ((float)iv == r) && iv > 0 && iv <= 128 &&
                      ((iv & (iv - 1)) == 0);
      const int j = ok ? __builtin_ctz(iv) : 0;
      jm[s] = j;
      seen |= ok ? (1 << j) : 0;
      fastok = fastok && ok;
    }
    fastok = fastok && (seen == 0xFF);       // bijective
#pragma unroll
    for (int j = 0; j < 8; ++j) {
      if (fastok) {
        int v = 0;
#pragma unroll
        for (int s = 0; s < 8; ++s) v += (jm[s] == j) ? s : 0;
        kof[j] = v;                          // kof = jm^{-1}
      } else {
        kof[j] = j;                          // identity for fallback path
      }
    }
  }

  // ---- input-side weights: fused f/k prenet pairs + yhat row pairs ----
  // wfk[k] = {TS*Wf1[k][h], TS*Wk1[k][h]}  (splat-x form: one chain, both nets)
  v2f wfk[8];
#pragma unroll
  for (int k = 0; k < 8; ++k)
    wfk[k] = v2f{TS * Wf1[k * HID + h], TS * Wk1[k * HID + h]};
  const float uf8 = TS * Wf1[8 * HID + h];
  const float uf9 = TS * Wf1[9 * HID + h];
  const v2f hb = v2f{TS * bf1[h], TS * bk1[h]};
  // wgp[k] = {Wg[k][0], Wg[k][1]}  (Wg row k; uniform)
  v2f wgp[8];
#pragma unroll
  for (int k = 0; k < 8; ++k) wgp[k] = v2f{Wg[2 * k], Wg[2 * k + 1]};
  const v2f bgp = v2f{bg[0], bg[1]};

  // ---- output side: permuted by kof (identity when fallback) ----
  v2f wf2p[4], bf2sp[4], wk2e[4], wk2o[4], bk2se[4], bk2so[4];
  {
    const float* wf2row = Wf2 + h * NX;
    const float* wk2row = Wk2 + h * (NX * 2);
#pragma unroll
    for (int p = 0; p < 4; ++p) {
      const int kl = kof[2 * p], kh = kof[2 * p + 1];
      wf2p[p]  = v2f{wf2row[kl], wf2row[kh]};
      bf2sp[p] = v2f{INV64 * bf2[kl], INV64 * bf2[kh]};
      wk2e[p]  = v2f{wk2row[2 * kl], wk2row[2 * kh]};
      wk2o[p]  = v2f{wk2row[2 * kl + 1], wk2row[2 * kh + 1]};
      bk2se[p] = v2f{INV64 * bk2[2 * kl], INV64 * bk2[2 * kh]};
      bk2so[p] = v2f{INV64 * bk2[2 * kl + 1], INV64 * bk2[2 * kh + 1]};
    }
  }

  const v2f* __restrict__ pu = reinterpret_cast<const v2f*>(u) + eb;
  const v2f* __restrict__ py = reinterpret_cast<const v2f*>(y) + eb;
  const int STR = B_SZ;

  v2f x2[4];
#pragma unroll
  for (int p = 0; p < 4; ++p) x2[p] = v2f{0.0f, 0.0f};

  v2f Au[4], Ay[4], Bu[4], By[4];

#define LOADG(SET_u, SET_y)                          \
  {                                                  \
    SET_u[0] = pu[0 * STR]; SET_u[1] = pu[1 * STR];  \
    SET_u[2] = pu[2 * STR]; SET_u[3] = pu[3 * STR];  \
    SET_y[0] = py[0 * STR]; SET_y[1] = py[1 * STR];  \
    SET_y[2] = py[2 * STR]; SET_y[3] = py[3 * STR];  \
    pu += 4 * STR; py += 4 * STR;                    \
  }

#define STEP(CU_, CY_)                                                        \
  {                                                                           \
    const v2f cu = (CU_);                                                     \
    const v2f cy = (CY_);                                                     \
    /* packed yhat: ya = sum_k splat(x[k]) * {Wg[k][0],Wg[k][1]} */           \
    v2f ya = pk_fma_s0lo(x2[0], wgp[0], bgp);                                 \
    pk_fma_acc_s1hi(ya, wgp[1], x2[0]);                                       \
    pk_fma_acc_s1lo(ya, wgp[2], x2[1]);                                       \
    pk_fma_acc_s1hi(ya, wgp[3], x2[1]);                                       \
    pk_fma_acc_s1lo(ya, wgp[4], x2[2]);                                       \
    pk_fma_acc_s1hi(ya, wgp[5], x2[2]);                                       \
    pk_fma_acc_s1lo(ya, wgp[6], x2[3]);                                       \
    pk_fma_acc_s1hi(ya, wgp[7], x2[3]);                                       \
    v2f ep;                                                                   \
    ep[0] = ya[0] - cy[0];                                                    \
    ep[1] = ya[1] - cy[1];                                                    \
    /* fused prenet: pre = sum_k splat(x[k]) * {f_k, k_k} (+u into f half) */ \
    v2f pre = pk_fma_s0lo(x2[0], wfk[0], hb);                                 \
    pk_fma_acc_s1hi(pre, wfk[1], x2[0]);                                      \
    pk_fma_acc_s1lo(pre, wfk[2], x2[1]);                                      \
    pk_fma_acc_s1hi(pre, wfk[3], x2[1]);                                      \
    pk_fma_acc_s1lo(pre, wfk[4], x2[2]);                                      \
    pk_fma_acc_s1hi(pre, wfk[5], x2[2]);                                      \
    pk_fma_acc_s1lo(pre, wfk[6], x2[3]);                                      \
    pk_fma_acc_s1hi(pre, wfk[7], x2[3]);                                      \
    pre[0] = fmaf(cu[0], uf8, pre[0]);                                        \
    pre[0] = fmaf(cu[1], uf9, pre[0]);                                        \
    const v2f hp = tanh_pair(pre[0], pre[1]);                                 \
    /* per-lane contributions: op_sel splats (PROVEN R6) */                   \
    float c0, c1, c2, c3, c4, c5, c6, c7;                                     \
    {                                                                         \
      v2f t0 = pk_fma_s0hi(hp, wk2e[0], bk2se[0]);                            \
      v2f t1 = pk_fma_s0hi(hp, wk2o[0], bk2so[0]);                            \
      v2f cp = pk_fma_s0lo(hp, wf2p[0], bf2sp[0]);                            \
      pk_fma_acc_s1lo(cp, t0, ep);                                            \
      pk_fma_acc_s1hi(cp, t1, ep);                                            \
      c0 = cp[0]; c1 = cp[1];                                                 \
    }                                                                         \
    {                                                                         \
      v2f t0 = pk_fma_s0hi(hp, wk2e[1], bk2se[1]);                            \
      v2f t1 = pk_fma_s0hi(hp, wk2o[1], bk2so[1]);                            \
      v2f cp = pk_fma_s0lo(hp, wf2p[1], bf2sp[1]);                            \
      pk_fma_acc_s1lo(cp, t0, ep);                                            \
      pk_fma_acc_s1hi(cp, t1, ep);                                            \
      c2 = cp[0]; c3 = cp[1];                                                 \
    }                                                                         \
    {                                                                         \
      v2f t0 = pk_fma_s0hi(hp, wk2e[2], bk2se[2]);                            \
      v2f t1 = pk_fma_s0hi(hp, wk2o[2], bk2so[2]);                            \
      v2f cp = pk_fma_s0lo(hp, wf2p[2], bf2sp[2]);                            \
      pk_fma_acc_s1lo(cp, t0, ep);                                            \
      pk_fma_acc_s1hi(cp, t1, ep);                                            \
      c4 = cp[0]; c5 = cp[1];                                                 \
    }                                                                         \
    {                                                                         \
      v2f t0 = pk_fma_s0hi(hp, wk2e[3], bk2se[3]);                            \
      v2f t1 = pk_fma_s0hi(hp, wk2o[3], bk2so[3]);                            \
      v2f cp = pk_fma_s0lo(hp, wf2p[3], bf2sp[3]);                            \
      pk_fma_acc_s1lo(cp, t0, ep);                                            \
      pk_fma_acc_s1hi(cp, t1, ep);                                            \
      c6 = cp[0]; c7 = cp[1];                                                 \
    }                                                                         \
    /* PROVEN swap32 fold */                                                  \
    swap32(c0, c4); float d0 = c0 + c4;                                       \
    swap32(c1, c5); float d1 = c1 + c5;                                       \
    swap32(c2, c6); float d2 = c2 + c6;                                       \
    swap32(c3, c7); float d3 = c3 + c7;                                       \
    if (fastok) {                                                             \
      /* PROVEN R12 two-level: swap16 fold + 4-stage builtin-DPP prefix */    \
      swap16(d0, d1); float ff = d0 + d1;                                     \
      swap16(d2, d3); float gg = d2 + d3;                                     \
      ff = prefix16(ff);                                                      \
      gg = prefix16(gg);                                                      \
      x2[0][0] += rlf(ff, 15); x2[0][1] += rlf(ff, 31);                       \
      x2[1][0] += rlf(ff, 47); x2[1][1] += rlf(ff, 63);                       \
      x2[2][0] += rlf(gg, 15); x2[2][1] += rlf(gg, 31);                       \
      x2[3][0] += rlf(gg, 47); x2[3][1] += rlf(gg, 63);                       \
    } else {                                                                  \
      /* exact R11 path (kof == identity) */                                  \
      d0 = half_reduce(d0); d1 = half_reduce(d1);                             \
      d2 = half_reduce(d2); d3 = half_reduce(d3);                             \
      x2[0][0] += rlf(d0, laneA); x2[0][1] += rlf(d1, laneA);                 \
      x2[1][0] += rlf(d2, laneA); x2[1][1] += rlf(d3, laneA);                 \
      x2[2][0] += rlf(d0, laneB); x2[2][1] += rlf(d1, laneB);                 \
      x2[3][0] += rlf(d2, laneB); x2[3][1] += rlf(d3, laneB);                 \
    }                                                                         \
  }

  LOADG(Au, Ay);
  LOADG(Bu, By);

  for (int it = 0; it < 255; ++it) {
    STEP(Au[0], Ay[0]); STEP(Au[1], Ay[1]); STEP(Au[2], Ay[2]); STEP(Au[3], Ay[3]);
    LOADG(Au, Ay);
    STEP(Bu[0], By[0]); STEP(Bu[1], By[1]); STEP(Bu[2], By[2]); STEP(Bu[3], By[3]);
    LOADG(Bu, By);
  }
  STEP(Au[0], Ay[0]); STEP(Au[1], Ay[1]); STEP(Au[2], Ay[2]); STEP(Au[3], Ay[3]);
  STEP(Bu[0], By[0]); STEP(Bu[1], By[1]); STEP(Bu[2], By[2]); STEP(Bu[3], By[3]);
#undef STEP
#undef LOADG

  if (h == 0) {
#pragma unroll
    for (int p = 0; p < 4; ++p) {
      out[eb * NX + 2 * p]     = x2[p][0];
      out[eb * NX + 2 * p + 1] = x2[p][1];
    }
  }
}

extern "C" void kernel_launch(void* const* d_in, const int* in_sizes, int n_in,
                              void* d_out, int out_size, void* d_ws, size_t ws_size,
                              hipStream_t stream) {
  const float* u   = (const float*)d_in[0];
  const float* y   = (const float*)d_in[1];
  const float* Wf1 = (const float*)d_in[2];
  const float* bf1 = (const float*)d_in[3];
  const float* Wf2 = (const float*)d_in[4];
  const float* bf2 = (const float*)d_in[5];
  const float* Wg  = (const float*)d_in[6];
  const float* bg  = (const float*)d_in[7];
  const float* Wk1 = (const float*)d_in[8];
  const float* bk1 = (const float*)d_in[9];
  const float* Wk2 = (const float*)d_in[10];
  const float* bk2 = (const float*)d_in[11];

  luen_kernel<<<dim3(B_SZ), dim3(HID), 0, stream>>>(
      u, y, Wf1, bf1, Wf2, bf2, Wg, bg, Wk1, bk1, Wk2, bk2, (float*)d_out);
}